// Round 3
// baseline (707.073 us; speedup 1.0000x reference)
//
#include <hip/hip_runtime.h>
#include <hip/hip_bf16.h>
#include <math.h>

#define N_NODES 100000
#define N_EDGES 1600000
#define IN_F 256
#define HID 32
#define OUTC 16

// ============ CSR build ============
__global__ __launch_bounds__(256) void k_zero(int* __restrict__ deg)
{
    const int i = blockIdx.x * 256 + threadIdx.x;
    if (i <= N_NODES) deg[i] = 0;
}

__global__ __launch_bounds__(256) void k_hist(const int* __restrict__ ei, int* __restrict__ deg)
{
    const int e = blockIdx.x * 256 + threadIdx.x;
    const int dst = ei[N_EDGES + e];
    atomicAdd(&deg[dst], 1);
}

// single block, 1024 threads: exclusive scan of deg -> row_start; deg becomes cursor (=row_start copy)
__global__ __launch_bounds__(1024) void k_scan(int* __restrict__ deg_cur, int* __restrict__ row_start)
{
    __shared__ int tot[1024];
    const int t = threadIdx.x;
    const int ELEMS = 98;                 // 1024*98 = 100352 >= 100000
    const int base = t * ELEMS;
    int s = 0;
    for (int i = 0; i < ELEMS; ++i) {
        const int idx = base + i;
        if (idx < N_NODES) s += deg_cur[idx];
    }
    tot[t] = s;
    __syncthreads();
    for (int off = 1; off < 1024; off <<= 1) {
        const int v = (t >= off) ? tot[t - off] : 0;
        __syncthreads();
        tot[t] += v;
        __syncthreads();
    }
    int run = (t > 0) ? tot[t - 1] : 0;   // exclusive prefix of this chunk
    for (int i = 0; i < ELEMS; ++i) {
        const int idx = base + i;
        if (idx < N_NODES) {
            const int d = deg_cur[idx];   // read BEFORE overwrite (same buffer)
            row_start[idx] = run;
            deg_cur[idx]   = run;         // cursor init
            run += d;
        }
    }
    if (t == 1023) row_start[N_NODES] = tot[1023];
}

__global__ __launch_bounds__(256) void k_fill(const int* __restrict__ ei,
                                              int* __restrict__ cursor, int* __restrict__ col)
{
    const int e = blockIdx.x * 256 + threadIdx.x;
    const int src = ei[e];
    const int dst = ei[N_EDGES + e];
    const int pos = atomicAdd(&cursor[dst], 1);
    col[pos] = src;
}

// ============ Layer 1 dense: h1 = x@W1a^T + b ; out1 = h1@W1b^T + b ============
__global__ __launch_bounds__(256) void k1_layer1_dense(
    const float* __restrict__ x,
    const float* __restrict__ w1a_w, const float* __restrict__ w1a_b,
    const float* __restrict__ w1b_w, const float* __restrict__ w1b_b,
    float* __restrict__ h1, float* __restrict__ out1)
{
    __shared__ float xs[64][260];
    __shared__ float ws[32][260];
    __shared__ float hs[64][33];
    __shared__ float wbs[32][33];

    const int t = threadIdx.x;
    const int node0 = blockIdx.x * 64;
    const int nrem = N_NODES - node0;

    for (int i = t; i < 32 * 256; i += 256)
        ws[i >> 8][i & 255] = w1a_w[i];
    for (int i = t; i < 32 * 32; i += 256)
        wbs[i >> 5][i & 31] = w1b_w[i];
    {
        const float4* xg = (const float4*)(x + (size_t)node0 * IN_F);
        for (int i = t; i < 64 * 64; i += 256) {
            int r = i >> 6, c4 = i & 63;
            float4 v = make_float4(0.f, 0.f, 0.f, 0.f);
            if (r < nrem) v = xg[(size_t)r * 64 + c4];
            ((float4*)&xs[r][0])[c4] = v;
        }
    }
    __syncthreads();

    const int o2 = t & 15;
    const int g  = t >> 4;

    float acc[4][2] = {};
    const float* wr0 = &ws[o2][0];
    const float* wr1 = &ws[o2 + 16][0];
    #pragma unroll 4
    for (int k = 0; k < 256; k += 4) {
        const float4 w40 = *(const float4*)(wr0 + k);
        const float4 w41 = *(const float4*)(wr1 + k);
        #pragma unroll
        for (int j = 0; j < 4; ++j) {
            const float4 x4 = *(const float4*)&xs[g * 4 + j][k];
            acc[j][0] += x4.x * w40.x + x4.y * w40.y + x4.z * w40.z + x4.w * w40.w;
            acc[j][1] += x4.x * w41.x + x4.y * w41.y + x4.z * w41.z + x4.w * w41.w;
        }
    }

    const float b0 = w1a_b[o2];
    const float b1 = w1a_b[o2 + 16];
    #pragma unroll
    for (int j = 0; j < 4; ++j) {
        const int ln = g * 4 + j;
        const float v0 = acc[j][0] + b0;
        const float v1 = acc[j][1] + b1;
        hs[ln][o2]      = v0;
        hs[ln][o2 + 16] = v1;
        if (ln < nrem) {
            h1[(size_t)(node0 + ln) * HID + o2]      = v0;
            h1[(size_t)(node0 + ln) * HID + o2 + 16] = v1;
        }
    }
    __syncthreads();

    const float bb0 = w1b_b[o2];
    const float bb1 = w1b_b[o2 + 16];
    float f[4][2] = {};
    for (int c = 0; c < 32; ++c) {
        const float wv0 = wbs[o2][c];
        const float wv1 = wbs[o2 + 16][c];
        #pragma unroll
        for (int j = 0; j < 4; ++j) {
            const float hv = hs[g * 4 + j][c];
            f[j][0] += hv * wv0;
            f[j][1] += hv * wv1;
        }
    }
    #pragma unroll
    for (int j = 0; j < 4; ++j) {
        const int ln = g * 4 + j;
        if (ln < nrem) {
            out1[(size_t)(node0 + ln) * HID + o2]      = f[j][0] + bb0;
            out1[(size_t)(node0 + ln) * HID + o2 + 16] = f[j][1] + bb1;
        }
    }
}

// ============ Gather-aggregate layer 1: out1[n] += sum_{e in row(n)} h1[col[e]] ============
__global__ __launch_bounds__(256) void k_agg32(const int* __restrict__ row_start,
                                               const int* __restrict__ col,
                                               const float* __restrict__ h1,
                                               float* __restrict__ out1)
{
    const int t = threadIdx.x;
    const int n = blockIdx.x * 8 + (t >> 5);
    const int c = t & 31;
    if (n >= N_NODES) return;
    const int e0 = row_start[n];
    const int e1 = row_start[n + 1];
    float acc = 0.f;
    for (int e = e0; e < e1; ++e) {
        const int s = col[e];
        acc += h1[(size_t)s * HID + c];
    }
    out1[(size_t)n * HID + c] += acc;
}

// ============ Layer 2 dense ============
__global__ __launch_bounds__(256) void k3_layer2_dense(
    const float* __restrict__ out1,
    const float* __restrict__ w2a_w, const float* __restrict__ w2a_b,
    const float* __restrict__ w2b_w, const float* __restrict__ w2b_b,
    float* __restrict__ h2, float* __restrict__ out2)
{
    __shared__ float rs[64][33];
    __shared__ float h2s[64][17];
    __shared__ float wa[16][33];
    __shared__ float wb[16][17];

    const int t = threadIdx.x;
    const int node0 = blockIdx.x * 64;
    const int nrem = N_NODES - node0;

    for (int i = t; i < 16 * 32; i += 256)
        wa[i >> 5][i & 31] = w2a_w[i];
    if (t < 16 * 16) wb[t >> 4][t & 15] = w2b_w[t];
    for (int i = t; i < 64 * 32; i += 256) {
        int r = i >> 5, c = i & 31;
        float v = 0.f;
        if (r < nrem) v = out1[(size_t)(node0 + r) * HID + c];
        rs[r][c] = fmaxf(v, 0.f);
    }
    __syncthreads();

    const int o = t & 15;
    const int g = t >> 4;

    const float ba = w2a_b[o];
    float acc[4] = {};
    for (int c = 0; c < 32; ++c) {
        const float w = wa[o][c];
        #pragma unroll
        for (int j = 0; j < 4; ++j) acc[j] += rs[g * 4 + j][c] * w;
    }
    #pragma unroll
    for (int j = 0; j < 4; ++j) {
        const int ln = g * 4 + j;
        const float v = acc[j] + ba;
        h2s[ln][o] = v;
        if (ln < nrem) h2[(size_t)(node0 + ln) * OUTC + o] = v;
    }
    __syncthreads();

    const float bbv = w2b_b[o];
    float f[4] = {};
    for (int c = 0; c < 16; ++c) {
        const float w = wb[o][c];
        #pragma unroll
        for (int j = 0; j < 4; ++j) f[j] += h2s[g * 4 + j][c] * w;
    }
    #pragma unroll
    for (int j = 0; j < 4; ++j) {
        const int ln = g * 4 + j;
        if (ln < nrem) out2[(size_t)(node0 + ln) * OUTC + o] = f[j] + bbv;
    }
}

// ============ Gather-aggregate layer 2 ============
__global__ __launch_bounds__(256) void k_agg16(const int* __restrict__ row_start,
                                               const int* __restrict__ col,
                                               const float* __restrict__ h2,
                                               float* __restrict__ out2)
{
    const int t = threadIdx.x;
    const int n = blockIdx.x * 16 + (t >> 4);
    const int c = t & 15;
    if (n >= N_NODES) return;
    const int e0 = row_start[n];
    const int e1 = row_start[n + 1];
    float acc = 0.f;
    for (int e = e0; e < e1; ++e) {
        const int s = col[e];
        acc += h2[(size_t)s * OUTC + c];
    }
    out2[(size_t)n * OUTC + c] += acc;
}

// ============ log_softmax ============
__global__ __launch_bounds__(256) void k5_log_softmax(float* __restrict__ out)
{
    const int n = blockIdx.x * 256 + threadIdx.x;
    if (n >= N_NODES) return;
    float4* p = (float4*)(out + (size_t)n * OUTC);
    float4 a0 = p[0], a1 = p[1], a2 = p[2], a3 = p[3];
    float v[16] = { a0.x, a0.y, a0.z, a0.w, a1.x, a1.y, a1.z, a1.w,
                    a2.x, a2.y, a2.z, a2.w, a3.x, a3.y, a3.z, a3.w };
    float m = v[0];
    #pragma unroll
    for (int i = 1; i < 16; ++i) m = fmaxf(m, v[i]);
    float s = 0.f;
    #pragma unroll
    for (int i = 0; i < 16; ++i) s += expf(v[i] - m);
    const float lse = m + logf(s);
    #pragma unroll
    for (int i = 0; i < 16; ++i) v[i] -= lse;
    p[0] = make_float4(v[0], v[1], v[2], v[3]);
    p[1] = make_float4(v[4], v[5], v[6], v[7]);
    p[2] = make_float4(v[8], v[9], v[10], v[11]);
    p[3] = make_float4(v[12], v[13], v[14], v[15]);
}

extern "C" void kernel_launch(void* const* d_in, const int* in_sizes, int n_in,
                              void* d_out, int out_size, void* d_ws, size_t ws_size,
                              hipStream_t stream)
{
    const float* x      = (const float*)d_in[0];
    const float* w1a_w  = (const float*)d_in[1];
    const float* w1a_b  = (const float*)d_in[2];
    const float* w1b_w  = (const float*)d_in[3];
    const float* w1b_b  = (const float*)d_in[4];
    const float* w2a_w  = (const float*)d_in[5];
    const float* w2a_b  = (const float*)d_in[6];
    const float* w2b_w  = (const float*)d_in[7];
    const float* w2b_b  = (const float*)d_in[8];
    const int*   ei     = (const int*)d_in[9];
    float* out = (float*)d_out;

    // workspace layout (32.8 MB):
    float* h1   = (float*)d_ws;                           // N*32 f32 = 12.8 MB (reused as h2 later)
    float* out1 = h1 + (size_t)N_NODES * HID;             // N*32 f32 = 12.8 MB
    int* deg_cur   = (int*)(out1 + (size_t)N_NODES * HID); // N+1 ints (deg, then cursor)
    int* row_start = deg_cur + (N_NODES + 1);              // N+1 ints
    int* col       = row_start + (N_NODES + 1);            // E ints = 6.4 MB
    float* h2 = h1;                                        // alias: h1 dead after k_agg32

    const int nblk = (N_NODES + 63) / 64;                 // 1563

    k_zero<<<(N_NODES + 256) / 256, 256, 0, stream>>>(deg_cur);
    k_hist<<<N_EDGES / 256, 256, 0, stream>>>(ei, deg_cur);
    k_scan<<<1, 1024, 0, stream>>>(deg_cur, row_start);
    k_fill<<<N_EDGES / 256, 256, 0, stream>>>(ei, deg_cur, col);

    k1_layer1_dense<<<nblk, 256, 0, stream>>>(x, w1a_w, w1a_b, w1b_w, w1b_b, h1, out1);
    k_agg32<<<(N_NODES + 7) / 8, 256, 0, stream>>>(row_start, col, h1, out1);
    k3_layer2_dense<<<nblk, 256, 0, stream>>>(out1, w2a_w, w2a_b, w2b_w, w2b_b, h2, out);
    k_agg16<<<(N_NODES + 15) / 16, 256, 0, stream>>>(row_start, col, h2, out);
    k5_log_softmax<<<(N_NODES + 255) / 256, 256, 0, stream>>>(out);
}

// Round 4
// 454.389 us; speedup vs baseline: 1.5561x; 1.5561x over previous
//
#include <hip/hip_runtime.h>
#include <hip/hip_bf16.h>
#include <math.h>

#define N_NODES 100000
#define N_EDGES 1600000
#define IN_F 256
#define HID 32
#define OUTC 16
#define NBLK_SCAN 98   // ceil(100000/1024)

// ============ CSR build ============
__global__ __launch_bounds__(256) void k_zero(int* __restrict__ deg)
{
    const int i = blockIdx.x * 256 + threadIdx.x;
    if (i <= N_NODES) deg[i] = 0;
}

__global__ __launch_bounds__(256) void k_hist(const int* __restrict__ ei, int* __restrict__ deg)
{
    const int e = blockIdx.x * 256 + threadIdx.x;
    const int dst = ei[N_EDGES + e];
    atomicAdd(&deg[dst], 1);
}

// Phase A: per-1024-chunk exclusive scan (LDS Hillis-Steele), write partial prefix + block sum
__global__ __launch_bounds__(1024) void k_scanA(const int* __restrict__ deg,
                                                int* __restrict__ part, int* __restrict__ bsum)
{
    __shared__ int sh[1024];
    const int t = threadIdx.x;
    const int idx = blockIdx.x * 1024 + t;
    const int v = (idx < N_NODES) ? deg[idx] : 0;
    sh[t] = v;
    __syncthreads();
    #pragma unroll
    for (int off = 1; off < 1024; off <<= 1) {
        const int u = (t >= off) ? sh[t - off] : 0;
        __syncthreads();
        sh[t] += u;
        __syncthreads();
    }
    if (idx < N_NODES) part[idx] = sh[t] - v;          // exclusive within chunk
    if (t == 1023) bsum[blockIdx.x] = sh[1023];
}

// Phase B: scan the 98 block sums (single small block)
__global__ __launch_bounds__(128) void k_scanB(int* __restrict__ bsum, int* __restrict__ boff,
                                               int* __restrict__ row_start)
{
    __shared__ int sh[128];
    const int t = threadIdx.x;
    const int v = (t < NBLK_SCAN) ? bsum[t] : 0;
    sh[t] = v;
    __syncthreads();
    #pragma unroll
    for (int off = 1; off < 128; off <<= 1) {
        const int u = (t >= off) ? sh[t - off] : 0;
        __syncthreads();
        sh[t] += u;
        __syncthreads();
    }
    if (t < NBLK_SCAN) boff[t] = sh[t] - v;            // exclusive block offset
    if (t == 127) row_start[N_NODES] = sh[127];        // total = N_EDGES
}

// Phase C: row_start = part + boff ; cursor = row_start
__global__ __launch_bounds__(1024) void k_scanC(const int* __restrict__ part,
                                                const int* __restrict__ boff,
                                                int* __restrict__ row_start,
                                                int* __restrict__ cursor)
{
    const int idx = blockIdx.x * 1024 + threadIdx.x;
    if (idx < N_NODES) {
        const int v = part[idx] + boff[blockIdx.x];
        row_start[idx] = v;
        cursor[idx]    = v;
    }
}

__global__ __launch_bounds__(256) void k_fill(const int* __restrict__ ei,
                                              int* __restrict__ cursor, int* __restrict__ col)
{
    const int e = blockIdx.x * 256 + threadIdx.x;
    const int src = ei[e];
    const int dst = ei[N_EDGES + e];
    const int pos = atomicAdd(&cursor[dst], 1);
    col[pos] = src;
}

// ============ Layer 1 dense: h1 = x@W1a^T + b ; out1 = h1@W1b^T + b ============
__global__ __launch_bounds__(256) void k1_layer1_dense(
    const float* __restrict__ x,
    const float* __restrict__ w1a_w, const float* __restrict__ w1a_b,
    const float* __restrict__ w1b_w, const float* __restrict__ w1b_b,
    float* __restrict__ h1, float* __restrict__ out1)
{
    __shared__ float xs[64][260];
    __shared__ float ws[32][260];
    __shared__ float hs[64][33];
    __shared__ float wbs[32][33];

    const int t = threadIdx.x;
    const int node0 = blockIdx.x * 64;
    const int nrem = N_NODES - node0;

    for (int i = t; i < 32 * 256; i += 256)
        ws[i >> 8][i & 255] = w1a_w[i];
    for (int i = t; i < 32 * 32; i += 256)
        wbs[i >> 5][i & 31] = w1b_w[i];
    {
        const float4* xg = (const float4*)(x + (size_t)node0 * IN_F);
        for (int i = t; i < 64 * 64; i += 256) {
            int r = i >> 6, c4 = i & 63;
            float4 v = make_float4(0.f, 0.f, 0.f, 0.f);
            if (r < nrem) v = xg[(size_t)r * 64 + c4];
            ((float4*)&xs[r][0])[c4] = v;
        }
    }
    __syncthreads();

    const int o2 = t & 15;
    const int g  = t >> 4;

    float acc[4][2] = {};
    const float* wr0 = &ws[o2][0];
    const float* wr1 = &ws[o2 + 16][0];
    #pragma unroll 4
    for (int k = 0; k < 256; k += 4) {
        const float4 w40 = *(const float4*)(wr0 + k);
        const float4 w41 = *(const float4*)(wr1 + k);
        #pragma unroll
        for (int j = 0; j < 4; ++j) {
            const float4 x4 = *(const float4*)&xs[g * 4 + j][k];
            acc[j][0] += x4.x * w40.x + x4.y * w40.y + x4.z * w40.z + x4.w * w40.w;
            acc[j][1] += x4.x * w41.x + x4.y * w41.y + x4.z * w41.z + x4.w * w41.w;
        }
    }

    const float b0 = w1a_b[o2];
    const float b1 = w1a_b[o2 + 16];
    #pragma unroll
    for (int j = 0; j < 4; ++j) {
        const int ln = g * 4 + j;
        const float v0 = acc[j][0] + b0;
        const float v1 = acc[j][1] + b1;
        hs[ln][o2]      = v0;
        hs[ln][o2 + 16] = v1;
        if (ln < nrem) {
            h1[(size_t)(node0 + ln) * HID + o2]      = v0;
            h1[(size_t)(node0 + ln) * HID + o2 + 16] = v1;
        }
    }
    __syncthreads();

    const float bb0 = w1b_b[o2];
    const float bb1 = w1b_b[o2 + 16];
    float f[4][2] = {};
    for (int c = 0; c < 32; ++c) {
        const float wv0 = wbs[o2][c];
        const float wv1 = wbs[o2 + 16][c];
        #pragma unroll
        for (int j = 0; j < 4; ++j) {
            const float hv = hs[g * 4 + j][c];
            f[j][0] += hv * wv0;
            f[j][1] += hv * wv1;
        }
    }
    #pragma unroll
    for (int j = 0; j < 4; ++j) {
        const int ln = g * 4 + j;
        if (ln < nrem) {
            out1[(size_t)(node0 + ln) * HID + o2]      = f[j][0] + bb0;
            out1[(size_t)(node0 + ln) * HID + o2 + 16] = f[j][1] + bb1;
        }
    }
}

// ============ Gather-aggregate layer 1: out1[n] += sum_{e in row(n)} h1[col[e]] ============
__global__ __launch_bounds__(256) void k_agg32(const int* __restrict__ row_start,
                                               const int* __restrict__ col,
                                               const float* __restrict__ h1,
                                               float* __restrict__ out1)
{
    const int t = threadIdx.x;
    const int n = blockIdx.x * 8 + (t >> 5);
    const int c = t & 31;
    if (n >= N_NODES) return;
    const int e0 = row_start[n];
    const int e1 = row_start[n + 1];
    float acc = 0.f;
    for (int e = e0; e < e1; ++e) {
        const int s = col[e];
        acc += h1[(size_t)s * HID + c];
    }
    out1[(size_t)n * HID + c] += acc;
}

// ============ Layer 2 dense ============
__global__ __launch_bounds__(256) void k3_layer2_dense(
    const float* __restrict__ out1,
    const float* __restrict__ w2a_w, const float* __restrict__ w2a_b,
    const float* __restrict__ w2b_w, const float* __restrict__ w2b_b,
    float* __restrict__ h2, float* __restrict__ out2)
{
    __shared__ float rs[64][33];
    __shared__ float h2s[64][17];
    __shared__ float wa[16][33];
    __shared__ float wb[16][17];

    const int t = threadIdx.x;
    const int node0 = blockIdx.x * 64;
    const int nrem = N_NODES - node0;

    for (int i = t; i < 16 * 32; i += 256)
        wa[i >> 5][i & 31] = w2a_w[i];
    if (t < 16 * 16) wb[t >> 4][t & 15] = w2b_w[t];
    for (int i = t; i < 64 * 32; i += 256) {
        int r = i >> 5, c = i & 31;
        float v = 0.f;
        if (r < nrem) v = out1[(size_t)(node0 + r) * HID + c];
        rs[r][c] = fmaxf(v, 0.f);
    }
    __syncthreads();

    const int o = t & 15;
    const int g = t >> 4;

    const float ba = w2a_b[o];
    float acc[4] = {};
    for (int c = 0; c < 32; ++c) {
        const float w = wa[o][c];
        #pragma unroll
        for (int j = 0; j < 4; ++j) acc[j] += rs[g * 4 + j][c] * w;
    }
    #pragma unroll
    for (int j = 0; j < 4; ++j) {
        const int ln = g * 4 + j;
        const float v = acc[j] + ba;
        h2s[ln][o] = v;
        if (ln < nrem) h2[(size_t)(node0 + ln) * OUTC + o] = v;
    }
    __syncthreads();

    const float bbv = w2b_b[o];
    float f[4] = {};
    for (int c = 0; c < 16; ++c) {
        const float w = wb[o][c];
        #pragma unroll
        for (int j = 0; j < 4; ++j) f[j] += h2s[g * 4 + j][c] * w;
    }
    #pragma unroll
    for (int j = 0; j < 4; ++j) {
        const int ln = g * 4 + j;
        if (ln < nrem) out2[(size_t)(node0 + ln) * OUTC + o] = f[j] + bbv;
    }
}

// ============ Gather-aggregate layer 2 + fused log_softmax ============
// 16 lanes per node hold the 16 channels; shfl_xor(width 16) for max/sum.
__global__ __launch_bounds__(256) void k_agg16_sm(const int* __restrict__ row_start,
                                                  const int* __restrict__ col,
                                                  const float* __restrict__ h2,
                                                  float* __restrict__ out2)
{
    const int t = threadIdx.x;
    const int n = blockIdx.x * 16 + (t >> 4);
    const int c = t & 15;
    if (n >= N_NODES) return;
    const int e0 = row_start[n];
    const int e1 = row_start[n + 1];
    float acc = 0.f;
    for (int e = e0; e < e1; ++e) {
        const int s = col[e];
        acc += h2[(size_t)s * OUTC + c];
    }
    const float val = out2[(size_t)n * OUTC + c] + acc;

    float m = val;
    #pragma unroll
    for (int off = 8; off > 0; off >>= 1)
        m = fmaxf(m, __shfl_xor(m, off, 16));
    float s = expf(val - m);
    #pragma unroll
    for (int off = 8; off > 0; off >>= 1)
        s += __shfl_xor(s, off, 16);
    const float lse = m + logf(s);
    out2[(size_t)n * OUTC + c] = val - lse;
}

extern "C" void kernel_launch(void* const* d_in, const int* in_sizes, int n_in,
                              void* d_out, int out_size, void* d_ws, size_t ws_size,
                              hipStream_t stream)
{
    const float* x      = (const float*)d_in[0];
    const float* w1a_w  = (const float*)d_in[1];
    const float* w1a_b  = (const float*)d_in[2];
    const float* w1b_w  = (const float*)d_in[3];
    const float* w1b_b  = (const float*)d_in[4];
    const float* w2a_w  = (const float*)d_in[5];
    const float* w2a_b  = (const float*)d_in[6];
    const float* w2b_w  = (const float*)d_in[7];
    const float* w2b_b  = (const float*)d_in[8];
    const int*   ei     = (const int*)d_in[9];
    float* out = (float*)d_out;

    // workspace layout (~33 MB):
    float* h1   = (float*)d_ws;                            // N*32 f32 = 12.8 MB (reused as h2)
    float* out1 = h1 + (size_t)N_NODES * HID;              // N*32 f32 = 12.8 MB
    int* deg_cur   = (int*)(out1 + (size_t)N_NODES * HID); // N+1 ints (deg -> cursor)
    int* row_start = deg_cur + (N_NODES + 1);              // N+1 ints
    int* col       = row_start + (N_NODES + 1);            // E ints = 6.4 MB
    int* part      = col + N_EDGES;                        // N ints (scan partial)
    int* bsum      = part + N_NODES;                       // NBLK_SCAN ints
    int* boff      = bsum + NBLK_SCAN;                     // NBLK_SCAN ints
    float* h2 = h1;                                        // alias: h1 dead after k_agg32

    const int nblk = (N_NODES + 63) / 64;                  // 1563

    k_zero<<<(N_NODES + 256) / 256, 256, 0, stream>>>(deg_cur);
    k_hist<<<N_EDGES / 256, 256, 0, stream>>>(ei, deg_cur);
    k_scanA<<<NBLK_SCAN, 1024, 0, stream>>>(deg_cur, part, bsum);
    k_scanB<<<1, 128, 0, stream>>>(bsum, boff, row_start);
    k_scanC<<<NBLK_SCAN, 1024, 0, stream>>>(part, boff, row_start, deg_cur);
    k_fill<<<N_EDGES / 256, 256, 0, stream>>>(ei, deg_cur, col);

    k1_layer1_dense<<<nblk, 256, 0, stream>>>(x, w1a_w, w1a_b, w1b_w, w1b_b, h1, out1);
    k_agg32<<<(N_NODES + 7) / 8, 256, 0, stream>>>(row_start, col, h1, out1);
    k3_layer2_dense<<<nblk, 256, 0, stream>>>(out1, w2a_w, w2a_b, w2b_w, w2b_b, h2, out);
    k_agg16_sm<<<(N_NODES + 15) / 16, 256, 0, stream>>>(row_start, col, h2, out);
}

// Round 5
// 416.299 us; speedup vs baseline: 1.6985x; 1.0915x over previous
//
#include <hip/hip_runtime.h>
#include <hip/hip_bf16.h>
#include <math.h>

#define N_NODES 100000
#define N_EDGES 1600000
#define IN_F 256
#define HID 32
#define OUTC 16
#define NBLK_SCAN 98   // ceil(100000/1024)

typedef unsigned short ushort_t;
typedef unsigned int uint_t;

__device__ inline ushort_t f2bf(float f) {
    union { float f; uint_t u; } v; v.f = f;
    uint_t r = v.u + 0x7fff + ((v.u >> 16) & 1);   // round-to-nearest-even
    return (ushort_t)(r >> 16);
}
__device__ inline float bf2f(ushort_t h) {
    union { uint_t u; float f; } v; v.u = (uint_t)h << 16;
    return v.f;
}

// ============ CSR build ============
__global__ __launch_bounds__(256) void k_zero(int* __restrict__ deg)
{
    const int i = blockIdx.x * 256 + threadIdx.x;
    if (i <= N_NODES) deg[i] = 0;
}

__global__ __launch_bounds__(256) void k_hist(const int* __restrict__ ei, int* __restrict__ deg)
{
    const int e = blockIdx.x * 256 + threadIdx.x;
    const int dst = ei[N_EDGES + e];
    atomicAdd(&deg[dst], 1);
}

__global__ __launch_bounds__(1024) void k_scanA(const int* __restrict__ deg,
                                                int* __restrict__ part, int* __restrict__ bsum)
{
    __shared__ int sh[1024];
    const int t = threadIdx.x;
    const int idx = blockIdx.x * 1024 + t;
    const int v = (idx < N_NODES) ? deg[idx] : 0;
    sh[t] = v;
    __syncthreads();
    #pragma unroll
    for (int off = 1; off < 1024; off <<= 1) {
        const int u = (t >= off) ? sh[t - off] : 0;
        __syncthreads();
        sh[t] += u;
        __syncthreads();
    }
    if (idx < N_NODES) part[idx] = sh[t] - v;
    if (t == 1023) bsum[blockIdx.x] = sh[1023];
}

__global__ __launch_bounds__(128) void k_scanB(int* __restrict__ bsum, int* __restrict__ boff,
                                               int* __restrict__ row_start)
{
    __shared__ int sh[128];
    const int t = threadIdx.x;
    const int v = (t < NBLK_SCAN) ? bsum[t] : 0;
    sh[t] = v;
    __syncthreads();
    #pragma unroll
    for (int off = 1; off < 128; off <<= 1) {
        const int u = (t >= off) ? sh[t - off] : 0;
        __syncthreads();
        sh[t] += u;
        __syncthreads();
    }
    if (t < NBLK_SCAN) boff[t] = sh[t] - v;
    if (t == 127) row_start[N_NODES] = sh[127];
}

__global__ __launch_bounds__(1024) void k_scanC(const int* __restrict__ part,
                                                const int* __restrict__ boff,
                                                int* __restrict__ row_start,
                                                int* __restrict__ cursor)
{
    const int idx = blockIdx.x * 1024 + threadIdx.x;
    if (idx < N_NODES) {
        const int v = part[idx] + boff[blockIdx.x];
        row_start[idx] = v;
        cursor[idx]    = v;
    }
}

__global__ __launch_bounds__(256) void k_fill(const int* __restrict__ ei,
                                              int* __restrict__ cursor, int* __restrict__ col)
{
    const int e = blockIdx.x * 256 + threadIdx.x;
    const int src = ei[e];
    const int dst = ei[N_EDGES + e];
    const int pos = atomicAdd(&cursor[dst], 1);
    col[pos] = src;
}

// ============ Layer 1: h1 = x@W1a^T + b ; out1 = h1@W1b^T + b ============
// Register-blocked: 256 threads, 256 nodes/block, thread = 4 nodes x 8 outputs.
// LDS: W1a 32KB (broadcast) + h tile 36.9KB + W1b 4KB = ~73KB -> 2 blocks/CU.
__global__ __launch_bounds__(256) void k1_layer1_dense(
    const float* __restrict__ x,
    const float* __restrict__ w1a_w, const float* __restrict__ w1a_b,
    const float* __restrict__ w1b_w, const float* __restrict__ w1b_b,
    ushort_t* __restrict__ h1b, float* __restrict__ out1)
{
    __shared__ float ws[32][256];    // W1a, broadcast reads -> no pad needed
    __shared__ float hs[256][36];    // h tile, stride 36 (16B-aligned rows, spread banks)
    __shared__ float wbs[32][32];    // W1b

    const int t  = threadIdx.x;
    const int og = t & 3;            // output group: channels og*8 .. og*8+7
    const int ng = t >> 2;           // node group 0..63 -> nodes ng*4 .. ng*4+3
    const int o0 = og * 8;
    const int node0 = blockIdx.x * 256;

    {
        const float4* wsrc = (const float4*)w1a_w;
        float4* wdst = (float4*)&ws[0][0];
        for (int i = t; i < 2048; i += 256) wdst[i] = wsrc[i];
        const float4* bsrc = (const float4*)w1b_w;
        float4* bdst = (float4*)&wbs[0][0];
        if (t < 256) bdst[t] = bsrc[t];
    }
    __syncthreads();

    int nid[4]; bool val[4];
    #pragma unroll
    for (int j = 0; j < 4; ++j) { nid[j] = node0 + ng * 4 + j; val[j] = nid[j] < N_NODES; }

    // ---- GEMM1: acc[j][o] = x[nid[j]] . w1a[o0+o] ----
    float acc[4][8] = {};
    for (int kc = 0; kc < 64; kc += 2) {
        float4 xs4[4][2];
        #pragma unroll
        for (int j = 0; j < 4; ++j) {
            if (val[j]) {
                const float4* xr = (const float4*)(x + (size_t)nid[j] * IN_F);
                xs4[j][0] = xr[kc];
                xs4[j][1] = xr[kc + 1];
            } else {
                xs4[j][0] = make_float4(0.f, 0.f, 0.f, 0.f);
                xs4[j][1] = make_float4(0.f, 0.f, 0.f, 0.f);
            }
        }
        #pragma unroll
        for (int u = 0; u < 2; ++u) {
            const int k4 = (kc + u) * 4;
            #pragma unroll
            for (int o = 0; o < 8; ++o) {
                const float4 w4 = *(const float4*)&ws[o0 + o][k4];
                #pragma unroll
                for (int j = 0; j < 4; ++j) {
                    acc[j][o] += xs4[j][u].x * w4.x + xs4[j][u].y * w4.y
                               + xs4[j][u].z * w4.z + xs4[j][u].w * w4.w;
                }
            }
        }
    }

    #pragma unroll
    for (int o = 0; o < 8; ++o) {
        const float b = w1a_b[o0 + o];
        #pragma unroll
        for (int j = 0; j < 4; ++j) acc[j][o] += b;
    }

    // write h to LDS (always: values are defined) and to global h1 (bf16, guarded)
    #pragma unroll
    for (int j = 0; j < 4; ++j) {
        const int ln = ng * 4 + j;
        *(float4*)&hs[ln][o0]     = make_float4(acc[j][0], acc[j][1], acc[j][2], acc[j][3]);
        *(float4*)&hs[ln][o0 + 4] = make_float4(acc[j][4], acc[j][5], acc[j][6], acc[j][7]);
        if (val[j]) {
            uint4 pk;
            pk.x = (uint_t)f2bf(acc[j][0]) | ((uint_t)f2bf(acc[j][1]) << 16);
            pk.y = (uint_t)f2bf(acc[j][2]) | ((uint_t)f2bf(acc[j][3]) << 16);
            pk.z = (uint_t)f2bf(acc[j][4]) | ((uint_t)f2bf(acc[j][5]) << 16);
            pk.w = (uint_t)f2bf(acc[j][6]) | ((uint_t)f2bf(acc[j][7]) << 16);
            *(uint4*)(h1b + (size_t)nid[j] * HID + o0) = pk;
        }
    }
    __syncthreads();

    // ---- GEMM2: f[j][o] = h[nid[j]] . w1b[o0+o] + b ----
    float f[4][8] = {};
    #pragma unroll 2
    for (int c4 = 0; c4 < 8; ++c4) {
        float4 h4[4];
        #pragma unroll
        for (int j = 0; j < 4; ++j) h4[j] = *(const float4*)&hs[ng * 4 + j][c4 * 4];
        #pragma unroll
        for (int o = 0; o < 8; ++o) {
            const float4 w4 = *(const float4*)&wbs[o0 + o][c4 * 4];
            #pragma unroll
            for (int j = 0; j < 4; ++j)
                f[j][o] += h4[j].x * w4.x + h4[j].y * w4.y + h4[j].z * w4.z + h4[j].w * w4.w;
        }
    }
    #pragma unroll
    for (int o = 0; o < 8; ++o) {
        const float b = w1b_b[o0 + o];
        #pragma unroll
        for (int j = 0; j < 4; ++j) f[j][o] += b;
    }
    #pragma unroll
    for (int j = 0; j < 4; ++j) {
        if (val[j]) {
            float* dst = out1 + (size_t)nid[j] * HID + o0;
            *(float4*)dst       = make_float4(f[j][0], f[j][1], f[j][2], f[j][3]);
            *(float4*)(dst + 4) = make_float4(f[j][4], f[j][5], f[j][6], f[j][7]);
        }
    }
}

// ============ Gather-aggregate layer 1 (bf16 h1) ============
__global__ __launch_bounds__(256) void k_agg32(const int* __restrict__ row_start,
                                               const int* __restrict__ col,
                                               const ushort_t* __restrict__ h1b,
                                               float* __restrict__ out1)
{
    const int t = threadIdx.x;
    const int n = blockIdx.x * 8 + (t >> 5);
    const int c = t & 31;
    if (n >= N_NODES) return;
    const int e0 = row_start[n];
    const int e1 = row_start[n + 1];
    float acc = 0.f;
    for (int e = e0; e < e1; ++e) {
        const int s = col[e];
        acc += bf2f(h1b[(size_t)s * HID + c]);
    }
    out1[(size_t)n * HID + c] += acc;
}

// ============ Layer 2 dense: h2 = relu(out1)@W2a^T + b ; out = h2@W2b^T + b ============
__global__ __launch_bounds__(256) void k3_layer2_dense(
    const float* __restrict__ out1,
    const float* __restrict__ w2a_w, const float* __restrict__ w2a_b,
    const float* __restrict__ w2b_w, const float* __restrict__ w2b_b,
    ushort_t* __restrict__ h2b, float* __restrict__ out2)
{
    __shared__ float rs[64][33];
    __shared__ float h2s[64][17];
    __shared__ float wa[16][33];
    __shared__ float wb[16][17];

    const int t = threadIdx.x;
    const int node0 = blockIdx.x * 64;
    const int nrem = N_NODES - node0;

    for (int i = t; i < 16 * 32; i += 256)
        wa[i >> 5][i & 31] = w2a_w[i];
    if (t < 16 * 16) wb[t >> 4][t & 15] = w2b_w[t];
    for (int i = t; i < 64 * 32; i += 256) {
        int r = i >> 5, c = i & 31;
        float v = 0.f;
        if (r < nrem) v = out1[(size_t)(node0 + r) * HID + c];
        rs[r][c] = fmaxf(v, 0.f);
    }
    __syncthreads();

    const int o = t & 15;
    const int g = t >> 4;

    const float ba = w2a_b[o];
    float acc[4] = {};
    for (int c = 0; c < 32; ++c) {
        const float w = wa[o][c];
        #pragma unroll
        for (int j = 0; j < 4; ++j) acc[j] += rs[g * 4 + j][c] * w;
    }
    #pragma unroll
    for (int j = 0; j < 4; ++j) {
        const int ln = g * 4 + j;
        const float v = acc[j] + ba;
        h2s[ln][o] = v;
        if (ln < nrem) h2b[(size_t)(node0 + ln) * OUTC + o] = f2bf(v);
    }
    __syncthreads();

    const float bbv = w2b_b[o];
    float f[4] = {};
    for (int c = 0; c < 16; ++c) {
        const float w = wb[o][c];
        #pragma unroll
        for (int j = 0; j < 4; ++j) f[j] += h2s[g * 4 + j][c] * w;
    }
    #pragma unroll
    for (int j = 0; j < 4; ++j) {
        const int ln = g * 4 + j;
        if (ln < nrem) out2[(size_t)(node0 + ln) * OUTC + o] = f[j] + bbv;
    }
}

// ============ Gather-aggregate layer 2 (bf16 h2) + fused log_softmax ============
__global__ __launch_bounds__(256) void k_agg16_sm(const int* __restrict__ row_start,
                                                  const int* __restrict__ col,
                                                  const ushort_t* __restrict__ h2b,
                                                  float* __restrict__ out2)
{
    const int t = threadIdx.x;
    const int n = blockIdx.x * 16 + (t >> 4);
    const int c = t & 15;
    if (n >= N_NODES) return;
    const int e0 = row_start[n];
    const int e1 = row_start[n + 1];
    float acc = 0.f;
    for (int e = e0; e < e1; ++e) {
        const int s = col[e];
        acc += bf2f(h2b[(size_t)s * OUTC + c]);
    }
    const float val = out2[(size_t)n * OUTC + c] + acc;

    float m = val;
    #pragma unroll
    for (int off = 8; off > 0; off >>= 1)
        m = fmaxf(m, __shfl_xor(m, off, 16));
    float s = expf(val - m);
    #pragma unroll
    for (int off = 8; off > 0; off >>= 1)
        s += __shfl_xor(s, off, 16);
    const float lse = m + logf(s);
    out2[(size_t)n * OUTC + c] = val - lse;
}

extern "C" void kernel_launch(void* const* d_in, const int* in_sizes, int n_in,
                              void* d_out, int out_size, void* d_ws, size_t ws_size,
                              hipStream_t stream)
{
    const float* x      = (const float*)d_in[0];
    const float* w1a_w  = (const float*)d_in[1];
    const float* w1a_b  = (const float*)d_in[2];
    const float* w1b_w  = (const float*)d_in[3];
    const float* w1b_b  = (const float*)d_in[4];
    const float* w2a_w  = (const float*)d_in[5];
    const float* w2a_b  = (const float*)d_in[6];
    const float* w2b_w  = (const float*)d_in[7];
    const float* w2b_b  = (const float*)d_in[8];
    const int*   ei     = (const int*)d_in[9];
    float* out = (float*)d_out;

    // workspace (~30 MB)
    float*    out1 = (float*)d_ws;                         // N*32 f32 = 12.8 MB
    ushort_t* h1b  = (ushort_t*)(out1 + (size_t)N_NODES * HID);  // N*32 bf16 = 6.4 MB
    ushort_t* h2b  = h1b + (size_t)N_NODES * HID;          // N*16 bf16 = 3.2 MB
    int* deg_cur   = (int*)(h2b + (size_t)N_NODES * OUTC); // N+1
    int* row_start = deg_cur + (N_NODES + 1);              // N+1
    int* col       = row_start + (N_NODES + 1);            // E = 6.4 MB
    int* part      = col + N_EDGES;                        // N
    int* bsum      = part + N_NODES;                       // NBLK_SCAN
    int* boff      = bsum + NBLK_SCAN;                     // NBLK_SCAN

    k_zero<<<(N_NODES + 256) / 256, 256, 0, stream>>>(deg_cur);
    k_hist<<<N_EDGES / 256, 256, 0, stream>>>(ei, deg_cur);
    k_scanA<<<NBLK_SCAN, 1024, 0, stream>>>(deg_cur, part, bsum);
    k_scanB<<<1, 128, 0, stream>>>(bsum, boff, row_start);
    k_scanC<<<NBLK_SCAN, 1024, 0, stream>>>(part, boff, row_start, deg_cur);
    k_fill<<<N_EDGES / 256, 256, 0, stream>>>(ei, deg_cur, col);

    k1_layer1_dense<<<(N_NODES + 255) / 256, 256, 0, stream>>>(x, w1a_w, w1a_b, w1b_w, w1b_b, h1b, out1);
    k_agg32<<<(N_NODES + 7) / 8, 256, 0, stream>>>(row_start, col, h1b, out1);
    k3_layer2_dense<<<(N_NODES + 63) / 64, 256, 0, stream>>>(out1, w2a_w, w2a_b, w2b_w, w2b_b, h2b, out);
    k_agg16_sm<<<(N_NODES + 15) / 16, 256, 0, stream>>>(row_start, col, h2b, out);
}